// Round 1
// 263.016 us; speedup vs baseline: 1.0018x; 1.0018x over previous
//
#include <hip/hip_runtime.h>
#include <math.h>

#define HDIM 256
#define KDIM 16
#define SDIM 200
#define BDIM 512
#define NROWS (BDIM * SDIM)   // 102400
#define TM 32                 // rows per block in kernel 1 (32KB LDS)

typedef __bf16 bf16x8 __attribute__((ext_vector_type(8)));
typedef __bf16 bf16x4 __attribute__((ext_vector_type(4)));
typedef float  f32x4  __attribute__((ext_vector_type(4)));

// ---------------------------------------------------------------------------
// Fused pack: W1, W2, W3 -> fragment-ready split-bf16 layout
//   dst[((k>>3)*N + n)*8 + (k&7)] = hi/lo bf16 of W[k*N + n]
// ---------------------------------------------------------------------------
__global__ __launch_bounds__(256) void pack_all(
    const float* __restrict__ W1, const float* __restrict__ W2,
    const float* __restrict__ W3,
    __bf16* __restrict__ w1h, __bf16* __restrict__ w1l,
    __bf16* __restrict__ w2h, __bf16* __restrict__ w2l,
    __bf16* __restrict__ w3h, __bf16* __restrict__ w3l)
{
    int gid = blockIdx.x * 256 + threadIdx.x;
    const float* src;
    __bf16 *oh, *ol;
    int e, N;
    if (gid < 65536)       { src = W1; oh = w1h; ol = w1l; e = gid;          N = 256; }
    else if (gid < 131072) { src = W2; oh = w2h; ol = w2l; e = gid - 65536;  N = 256; }
    else if (gid < 135168) { src = W3; oh = w3h; ol = w3l; e = gid - 131072; N = 16;  }
    else return;

    int j  = e & 7;
    int n  = (e >> 3) & (N - 1);
    int kg = e >> 3; kg = (N == 256) ? (kg >> 8) : (kg >> 4);
    int k  = kg * 8 + j;
    float v = src[k * N + n];
    __bf16 h = (__bf16)v;
    oh[e] = h;
    ol[e] = (__bf16)(v - (float)h);
}

// ---------------------------------------------------------------------------
// Kernel 1 v8: SWAPPED-OPERAND MFMA. mfma(W_frag, X_frag) instead of
// mfma(X_frag, W_frag): C layout becomes col=lane&15 -> X-row,
// row=quad*4+r -> 4 CONSECUTIVE h-columns per lane. Epilogue collapses
// from 64x ds_write_b16 per thread-layer to 16x ds_write_b64 (bf16x4),
// bias load becomes one f32x4 per n-tile. Fragment loads, staging
// swizzle, 3-pass split arithmetic, logits section: unchanged.
// ---------------------------------------------------------------------------
__global__ __launch_bounds__(256) void mlp_softk_mfma(
    const float* __restrict__ X, const int* __restrict__ mask,
    const __bf16* __restrict__ W1h, const __bf16* __restrict__ W1l,
    const float* __restrict__ b1,
    const __bf16* __restrict__ W2h, const __bf16* __restrict__ W2l,
    const float* __restrict__ b2,
    const __bf16* __restrict__ W3h, const __bf16* __restrict__ W3l,
    float* __restrict__ P)
{
    __shared__ __bf16 Ahi[TM * HDIM];   // 16 KB
    __shared__ __bf16 Alo[TM * HDIM];   // 16 KB

    const int tid  = threadIdx.x;
    const int lane = tid & 63;
    const int w    = tid >> 6;      // wave id: owns cols 64w..64w+63
    const int l15  = lane & 15;
    const int quad = lane >> 4;
    const long r0  = (long)blockIdx.x * TM;

    // ---- stage X tile -> LDS as split bf16 (swizzled) ----
    {
        const float4* Xt = (const float4*)(X + r0 * HDIM);
        #pragma unroll
        for (int t = 0; t < (TM * HDIM / 4) / 256; ++t) {
            int v4  = tid + t * 256;
            float4 f = Xt[v4];
            int row = v4 >> 6;            // 64 float4 per row
            int col = (v4 & 63) << 2;
            int kgs = (col >> 3) ^ (row & 31);
            int base = row * HDIM + kgs * 8 + (col & 7);
            __bf16 h0 = (__bf16)f.x, h1 = (__bf16)f.y,
                   h2 = (__bf16)f.z, h3 = (__bf16)f.w;
            bf16x4 hv = {h0, h1, h2, h3};
            bf16x4 lv = {(__bf16)(f.x - (float)h0), (__bf16)(f.y - (float)h1),
                         (__bf16)(f.z - (float)h2), (__bf16)(f.w - (float)h3)};
            *(bf16x4*)(&Ahi[base]) = hv;
            *(bf16x4*)(&Alo[base]) = lv;
        }
    }
    __syncthreads();

    f32x4 acc[2][4];

    auto layer = [&](const __bf16* __restrict__ Wh, const __bf16* __restrict__ Wl,
                     const float* __restrict__ bias) {
        #pragma unroll
        for (int mt = 0; mt < 2; ++mt)
            #pragma unroll
            for (int nt = 0; nt < 4; ++nt)
                acc[mt][nt] = (f32x4){0.f, 0.f, 0.f, 0.f};

        #pragma unroll
        for (int kc = 0; kc < 8; ++kc) {
            bf16x8 bh[4], bl[4], ah[2], al[2];
            #pragma unroll
            for (int nt = 0; nt < 4; ++nt) {
                int n  = w * 64 + nt * 16 + l15;
                int kg = kc * 4 + quad;
                bh[nt] = *(const bf16x8*)(Wh + (kg * HDIM + n) * 8);
                bl[nt] = *(const bf16x8*)(Wl + (kg * HDIM + n) * 8);
            }
            #pragma unroll
            for (int mt = 0; mt < 2; ++mt) {
                int row = mt * 16 + l15;
                int kgs = (kc * 4 + quad) ^ (row & 31);
                ah[mt] = *(const bf16x8*)(&Ahi[row * HDIM + kgs * 8]);
                al[mt] = *(const bf16x8*)(&Alo[row * HDIM + kgs * 8]);
            }
            // SWAPPED: A-operand = W fragment, B-operand = X fragment.
            // (A/B fragment index layouts are symmetric for 16x16x32.)
            #pragma unroll
            for (int mt = 0; mt < 2; ++mt)
                #pragma unroll
                for (int nt = 0; nt < 4; ++nt) {
                    acc[mt][nt] = __builtin_amdgcn_mfma_f32_16x16x32_bf16(
                        bh[nt], ah[mt], acc[mt][nt], 0, 0, 0);
                    acc[mt][nt] = __builtin_amdgcn_mfma_f32_16x16x32_bf16(
                        bh[nt], al[mt], acc[mt][nt], 0, 0, 0);
                    acc[mt][nt] = __builtin_amdgcn_mfma_f32_16x16x32_bf16(
                        bl[nt], ah[mt], acc[mt][nt], 0, 0, 0);
                }
        }
        __syncthreads();   // everyone done reading A before overwrite

        // C layout (swapped): m = mt*16 + (lane&15), n = w*64 + nt*16 + quad*4 + r
        // -> regs r=0..3 are 4 consecutive h-columns: one bf16x4 write per array.
        f32x4 bias4[4];
        #pragma unroll
        for (int nt = 0; nt < 4; ++nt)
            bias4[nt] = *(const f32x4*)(bias + w * 64 + nt * 16 + quad * 4);

        #pragma unroll
        for (int mt = 0; mt < 2; ++mt)
            #pragma unroll
            for (int nt = 0; nt < 4; ++nt) {
                int m   = mt * 16 + l15;
                int g   = w * 8 + nt * 2 + (quad >> 1);          // n>>3
                int idx = m * HDIM + ((g ^ (m & 31)) * 8) + (quad & 1) * 4;
                bf16x4 hv, lv;
                #pragma unroll
                for (int r = 0; r < 4; ++r) {
                    float v = fmaxf(acc[mt][nt][r] + bias4[nt][r], 0.f);
                    __bf16 h = (__bf16)v;
                    hv[r] = h;
                    lv[r] = (__bf16)(v - (float)h);
                }
                *(bf16x4*)(&Ahi[idx]) = hv;
                *(bf16x4*)(&Alo[idx]) = lv;
            }
        __syncthreads();
    };

    layer(W1h, W1l, b1);
    layer(W2h, W2l, b2);

    // ---- logits: waves 0,1 each handle one 16-row m-tile (TM=32) ----
    // (unswapped: want k across lanes for the shfl_xor softmax)
    if (w < 2) {
        f32x4 lg = {0.f, 0.f, 0.f, 0.f};
        #pragma unroll
        for (int kc = 0; kc < 8; ++kc) {
            int row = w * 16 + l15;
            int kg  = kc * 4 + quad;
            int kgs = kg ^ (row & 31);
            bf16x8 ah = *(const bf16x8*)(&Ahi[row * HDIM + kgs * 8]);
            bf16x8 al = *(const bf16x8*)(&Alo[row * HDIM + kgs * 8]);
            bf16x8 bh = *(const bf16x8*)(W3h + (kg * KDIM + l15) * 8);
            bf16x8 bl = *(const bf16x8*)(W3l + (kg * KDIM + l15) * 8);
            lg = __builtin_amdgcn_mfma_f32_16x16x32_bf16(ah, bh, lg, 0, 0, 0);
            lg = __builtin_amdgcn_mfma_f32_16x16x32_bf16(al, bh, lg, 0, 0, 0);
            lg = __builtin_amdgcn_mfma_f32_16x16x32_bf16(ah, bl, lg, 0, 0, 0);
        }

        // softmax over k: 16 lanes of a quad-group hold the 16 cols of a row
        #pragma unroll
        for (int r = 0; r < 4; ++r) {
            float v  = lg[r];
            float mx = v;
            mx = fmaxf(mx, __shfl_xor(mx, 1));
            mx = fmaxf(mx, __shfl_xor(mx, 2));
            mx = fmaxf(mx, __shfl_xor(mx, 4));
            mx = fmaxf(mx, __shfl_xor(mx, 8));
            float e = __expf(v - mx);
            float s = e;
            s += __shfl_xor(s, 1);
            s += __shfl_xor(s, 2);
            s += __shfl_xor(s, 4);
            s += __shfl_xor(s, 8);
            int grow = (int)r0 + w * 16 + quad * 4 + r;
            int mv   = mask[grow];
            float ov = mv ? (e / s) * 0.25f : -2500.0f;   // (-10000)/sqrt(16)
            P[(long)grow * KDIM + l15] = ov;
        }
    }
}

// ---------------------------------------------------------------------------
// Kernel 2 (UNCHANGED): 512 threads = 8 waves = (s-quarter sq, k-half kh).
// Lane owns a float4 of h (one wave covers all 256 h-cols -> 1KB coalesced
// X loads, 5 in flight via unroll). acc = 8 k x f32x4 = 32 VGPRs.
// Single-barrier LDS tree reduce over the 4 s-quarters.
// psum is aliased onto red (phases barrier-separated) to stay < 64KB LDS.
// ---------------------------------------------------------------------------
__global__ __launch_bounds__(512) void softs_agg_kernel(
    const float* __restrict__ X, const float* __restrict__ tf,
    const float* __restrict__ P, float* __restrict__ out)
{
    __shared__ float wl[SDIM * KDIM];          // 12.8 KB
    __shared__ float tfl[SDIM];                // 0.8 KB
    __shared__ float invk[KDIM];
    __shared__ float red[6 * 8 * HDIM];        // 48 KB: slot (sq-1)*2+kh
    float* psum = red;                         // alias (dead before red use)

    const int tid = threadIdx.x;
    const int b   = blockIdx.x;

    // ---- phase 1: column softmax over S (exp(-2500)==0 handles the mask) ----
    const float* Pb = P + (long)b * SDIM * KDIM;
    float ps = 0.f;
    #pragma unroll
    for (int t = 0; t < 7; ++t) {
        int i = tid + t * 512;
        if (i < SDIM * KDIM) {
            float e = __expf(Pb[i]);
            wl[i] = e;
            ps += e;
        }
    }
    psum[tid] = ps;
    if (tid < SDIM) tfl[tid] = tf[b * SDIM + tid];
    __syncthreads();

    if (tid < KDIM) {
        float s = 0.f;
        #pragma unroll
        for (int g = 0; g < 32; ++g) s += psum[tid + g * 16];   // 512%16==0
        invk[tid] = 1.f / s;
    }
    __syncthreads();

    #pragma unroll
    for (int t = 0; t < 7; ++t) {
        int i = tid + t * 512;
        if (i < SDIM * KDIM) wl[i] *= tfl[i >> 4] * invk[i & 15];
    }
    __syncthreads();

    // ---- phase 2: out[b,k,h] = sum_s X[b,s,h] * wl[s,k] ----
    const int wv = tid >> 6;
    const int sq = wv >> 1;      // s-quarter: [50*sq, 50*sq+50)
    const int kh = wv & 1;       // k-half: k in [8*kh, 8*kh+8)
    const int ln = tid & 63;     // lane -> h-cols 4*ln..4*ln+3

    f32x4 acc[8];
    #pragma unroll
    for (int j = 0; j < 8; ++j) acc[j] = (f32x4){0.f, 0.f, 0.f, 0.f};

    const f32x4* Xb4 = (const f32x4*)(X + (long)b * SDIM * HDIM);
    const f32x4* wl4 = (const f32x4*)wl;
    const int s0 = sq * 50;
    #pragma unroll 5
    for (int si = 0; si < 50; ++si) {
        int s = s0 + si;
        f32x4 x  = Xb4[s * 64 + ln];             // 1KB coalesced per wave
        f32x4 d0 = wl4[s * 4 + 2 * kh + 0];      // wave-uniform LDS b128
        f32x4 d1 = wl4[s * 4 + 2 * kh + 1];
        #pragma unroll
        for (int j = 0; j < 4; ++j) {
            acc[j]     += x * d0[j];             // k = 8kh + j
            acc[4 + j] += x * d1[j];             // k = 8kh + 4 + j
        }
    }

    // ---- tree reduce over s-quarters: sq>0 deposit, sq==0 sums + stores ----
    if (sq > 0) {
        float* rp = red + (((sq - 1) * 2 + kh) * 8) * HDIM;
        #pragma unroll
        for (int j = 0; j < 8; ++j)
            *(f32x4*)(rp + j * HDIM + 4 * ln) = acc[j];
    }
    __syncthreads();
    if (sq == 0) {
        #pragma unroll
        for (int p = 0; p < 3; ++p) {
            const float* rp = red + ((p * 2 + kh) * 8) * HDIM;
            #pragma unroll
            for (int j = 0; j < 8; ++j)
                acc[j] += *(const f32x4*)(rp + j * HDIM + 4 * ln);
        }
        float* ob = out + (long)b * KDIM * HDIM + kh * 8 * HDIM;
        #pragma unroll
        for (int j = 0; j < 8; ++j)
            *(f32x4*)(ob + j * HDIM + 4 * ln) = acc[j];
    }
}

extern "C" void kernel_launch(void* const* d_in, const int* in_sizes, int n_in,
                              void* d_out, int out_size, void* d_ws, size_t ws_size,
                              hipStream_t stream) {
    (void)in_sizes; (void)n_in; (void)out_size; (void)ws_size;
    const float* X    = (const float*)d_in[0];
    const int*   mask = (const int*)  d_in[1];
    const float* tf   = (const float*)d_in[2];
    const float* W1   = (const float*)d_in[3];
    const float* b1   = (const float*)d_in[4];
    const float* W2   = (const float*)d_in[5];
    const float* b2   = (const float*)d_in[6];
    const float* W3   = (const float*)d_in[7];
    float* out = (float*)d_out;

    char* ws = (char*)d_ws;
    float*  P   = (float*)ws;                          // 102400*16*4 = 6,553,600 B
    __bf16* w1h = (__bf16*)(ws + 6553600);             // 65536 elems each
    __bf16* w1l = w1h + 65536;
    __bf16* w2h = w1l + 65536;
    __bf16* w2l = w2h + 65536;
    __bf16* w3h = w2l + 65536;                         // 4096 elems each
    __bf16* w3l = w3h + 4096;

    pack_all<<<528, 256, 0, stream>>>(W1, W2, W3, w1h, w1l, w2h, w2l, w3h, w3l);
    mlp_softk_mfma<<<NROWS / TM, 256, 0, stream>>>(X, mask, w1h, w1l, b1,
                                                   w2h, w2l, b2, w3h, w3l, P);
    softs_agg_kernel<<<BDIM, 512, 0, stream>>>(X, tf, P, out);
}